// Round 9
// baseline (444.888 us; speedup 1.0000x reference)
//
#include <hip/hip_runtime.h>
#include <stdint.h>

typedef unsigned short ushort_t;
typedef short bf16x4 __attribute__((ext_vector_type(4)));
typedef short bf16x8 __attribute__((ext_vector_type(8)));
typedef float f32x4 __attribute__((ext_vector_type(4)));
typedef float f32x16 __attribute__((ext_vector_type(16)));
typedef float f32x4v __attribute__((ext_vector_type(4)));

// ---------- helpers ----------
__device__ __forceinline__ ushort_t f2bf(float f) {
  unsigned int u = __builtin_bit_cast(unsigned int, f);
  u += 0x7fffu + ((u >> 16) & 1u);
  return (ushort_t)(u >> 16);
}
__device__ __forceinline__ float bf2f(ushort_t h) {
  unsigned int u = ((unsigned int)h) << 16;
  return __builtin_bit_cast(float, u);
}
__device__ __forceinline__ float exp2_hw(float x) {
  return __builtin_amdgcn_exp2f(x);  // v_exp_f32: D = 2^S0
}
__device__ __forceinline__ void load_lds16(const void* g, void* l) {
  __builtin_amdgcn_global_load_lds(
      (const __attribute__((address_space(1))) void*)g,
      (__attribute__((address_space(3))) void*)l, 16, 0, 0);
}

// ---------- x fp32 -> bf16 ----------
__global__ __launch_bounds__(256) void cvt_x_kernel(const float* __restrict__ x,
                                                    ushort_t* __restrict__ xb) {
  int i = blockIdx.x * 256 + threadIdx.x;  // each thread: 8 elems
  const f32x4v* xv = (const f32x4v*)x;
  f32x4v a = xv[2 * i], b = xv[2 * i + 1];
  bf16x8 o;
  o[0] = (short)f2bf(a[0]); o[1] = (short)f2bf(a[1]);
  o[2] = (short)f2bf(a[2]); o[3] = (short)f2bf(a[3]);
  o[4] = (short)f2bf(b[0]); o[5] = (short)f2bf(b[1]);
  o[6] = (short)f2bf(b[2]); o[7] = (short)f2bf(b[3]);
  ((bf16x8*)xb)[i] = o;
}

// ---------- weight fp32 [R][C] -> bf16 transposed [C][R] ----------
__global__ __launch_bounds__(256) void tr_cvt_kernel(const float* __restrict__ src,
                                                     ushort_t* __restrict__ dst,
                                                     int R, int C) {
  __shared__ float tile[64][65];
  int r0 = blockIdx.y * 64, c0 = blockIdx.x * 64;
  int t = threadIdx.x;
#pragma unroll
  for (int i = 0; i < 16; i++) {
    int idx = t + i * 256;
    int r = idx >> 6, c = idx & 63;
    tile[r][c] = src[(size_t)(r0 + r) * C + c0 + c];
  }
  __syncthreads();
#pragma unroll
  for (int i = 0; i < 16; i++) {
    int idx = t + i * 256;
    int cr = idx >> 6, cc = idx & 63;
    dst[(size_t)(c0 + cr) * R + r0 + cc] = f2bf(tile[cc][cr]);
  }
}

// ---------- RoPE in-place on C1 (Q cols 0..4095 pre-scaled by scale*log2e) ----------
__global__ __launch_bounds__(256) void rope_kernel(ushort_t* __restrict__ C1,
                                                   const float* __restrict__ cosb,
                                                   const float* __restrict__ sinb) {
  int idx = blockIdx.x * 256 + threadIdx.x;  // 2048 * 640
  int s = idx / 640;
  int col0 = (idx % 640) * 8;
  int i0 = (col0 & 127) >> 1;
  const float qs = (col0 < 4096) ? 0.12753055296570565f : 1.0f;  // scale*log2e
  ushort_t* p = C1 + (size_t)s * 6144 + col0;
  bf16x8 v = *(const bf16x8*)p;
  bf16x8 o;
  const float* cr = cosb + s * 64 + i0;
  const float* sr = sinb + s * 64 + i0;
#pragma unroll
  for (int j = 0; j < 4; j++) {
    float tr = bf2f((ushort_t)v[2 * j]);
    float ti = bf2f((ushort_t)v[2 * j + 1]);
    float c = cr[j], sn = sr[j];
    o[2 * j] = (short)f2bf((tr * c - ti * sn) * qs);
    o[2 * j + 1] = (short)f2bf((tr * sn + ti * c) * qs);
  }
  *(bf16x8*)p = o;
}

// ---------- V part of C1 -> VT [1024][2048] (row = hk*128+d, col = s) ----------
__global__ __launch_bounds__(256) void trv_kernel(const ushort_t* __restrict__ C1,
                                                  ushort_t* __restrict__ VT) {
  __shared__ ushort_t tile[64][65];
  int c0 = blockIdx.x * 64;  // within 1024
  int r0 = blockIdx.y * 64;  // within 2048
  int t = threadIdx.x;
#pragma unroll
  for (int i = 0; i < 16; i++) {
    int idx = t + i * 256;
    int r = idx >> 6, c = idx & 63;
    tile[r][c] = C1[(size_t)(r0 + r) * 6144 + 5120 + c0 + c];
  }
  __syncthreads();
#pragma unroll
  for (int i = 0; i < 16; i++) {
    int idx = t + i * 256;
    int cr = idx >> 6, cc = idx & 63;
    VT[(size_t)(c0 + cr) * 2048 + r0 + cc] = tile[cc][cr];
  }
}

// ---------- GEMM 256x256 deep-pipelined (T1+T2+T3/T4+T5) ----------
// C[M][ldc] = A[M][K] * BT[N][K]^T. Requires M%256==0, N%256==0, K%64==0,
// grid = (M/256)*(N/256) 1D with grid%8==0. 512 thr, 8 waves (2M x 4N),
// per-wave 128x64 output. LDS 128KB: 2-tile double buffer, XOR-swizzled
// (linear global_load_lds dest + pre-swizzled global source; swizzled ds_read).
// Pipeline: stage(t+2) issued after compute(t); vmcnt(8) (counted, never 0
// mid-loop) + raw s_barrier -> one tile of compute hides staging latency.
template <typename OutT>
__global__ __launch_bounds__(512, 1) void gemm256_kernel(const ushort_t* __restrict__ A,
                                                         const ushort_t* __restrict__ BT,
                                                         OutT* __restrict__ C,
                                                         int M, int N, int K, int ldc) {
  __shared__ ushort_t As[2][256 * 64];  // 64KB
  __shared__ ushort_t Bs[2][256 * 64];  // 64KB
  const int nbx = N >> 8;
  const int nwg = gridDim.x;
  const int id = blockIdx.x;
  const int wg = (id & 7) * (nwg >> 3) + (id >> 3);  // XCD-contiguous (nwg%8==0)
  const int brow = (wg / nbx) << 8, bcol = (wg % nbx) << 8;
  const int tid = threadIdx.x, w = tid >> 6, lane = tid & 63;
  const int wr = w >> 2, wc = w & 3;
  const int lr = lane & 15, lk = lane >> 4;

  const ushort_t* Ab = A + (size_t)brow * K;
  const ushort_t* Bb = BT + (size_t)bcol * K;

  // stage K-tile t (256 rows x 64 cols of A and BT) into buffer buf.
  // LDS linear: chunk L holds global chunk (L&7)^(r&7) of row r=L>>3.
  auto stage = [&](int t, int buf) {
    const int kk = t << 6;
#pragma unroll
    for (int i = 0; i < 4; ++i) {
      int L = i * 512 + tid;
      int r = L >> 3, sc = L & 7;
      load_lds16(Ab + (size_t)r * K + kk + ((sc ^ (r & 7)) << 3), (char*)&As[buf][0] + L * 16);
    }
#pragma unroll
    for (int i = 0; i < 4; ++i) {
      int L = i * 512 + tid;
      int r = L >> 3, sc = L & 7;
      load_lds16(Bb + (size_t)r * K + kk + ((sc ^ (r & 7)) << 3), (char*)&Bs[buf][0] + L * 16);
    }
  };

  f32x4 acc[8][4] = {};
  const int NT = K >> 6;

  stage(0, 0);
  stage(1, 1);
  asm volatile("s_waitcnt vmcnt(8)" ::: "memory");  // tile0 complete (tile1 in flight)
  asm volatile("s_barrier" ::: "memory");

  for (int t = 0; t < NT; ++t) {
    const int cur = t & 1;
    const char* Ac = (const char*)&As[cur][0];
    const char* Bc = (const char*)&Bs[cur][0];
    // B-fragments once per K-tile (live across the 4 phases)
    bf16x8 bfr[4][2];
#pragma unroll
    for (int n = 0; n < 4; ++n)
#pragma unroll
      for (int ks = 0; ks < 2; ++ks) {
        int rB = wc * 64 + n * 16 + lr;
        bfr[n][ks] = *(const bf16x8*)(Bc + rB * 128 + (((ks * 4 + lk) ^ (rB & 7)) << 4));
      }
    // 4 phases: 2 m-frags x 4 n-frags x 2 k-slots = 16 MFMA each
#pragma unroll
    for (int p = 0; p < 4; ++p) {
      bf16x8 af[2][2];
#pragma unroll
      for (int dm = 0; dm < 2; ++dm)
#pragma unroll
        for (int ks = 0; ks < 2; ++ks) {
          int rA = wr * 128 + (p * 2 + dm) * 16 + lr;
          af[dm][ks] = *(const bf16x8*)(Ac + rA * 128 + (((ks * 4 + lk) ^ (rA & 7)) << 4));
        }
      __builtin_amdgcn_s_setprio(1);
#pragma unroll
      for (int dm = 0; dm < 2; ++dm)
#pragma unroll
        for (int n = 0; n < 4; ++n)
#pragma unroll
          for (int ks = 0; ks < 2; ++ks)
            acc[p * 2 + dm][n] = __builtin_amdgcn_mfma_f32_16x16x32_bf16(
                af[dm][ks], bfr[n][ks], acc[p * 2 + dm][n], 0, 0, 0);
      __builtin_amdgcn_s_setprio(0);
    }
    asm volatile("s_barrier" ::: "memory");  // all waves done reading buf[cur]
    if (t + 2 < NT) {
      stage(t + 2, cur);                              // overwrite freed buffer
      asm volatile("s_waitcnt vmcnt(8)" ::: "memory");  // tile t+1 complete
    } else {
      asm volatile("s_waitcnt vmcnt(0)" ::: "memory");  // drain tail
    }
    asm volatile("s_barrier" ::: "memory");  // tile t+1 visible to all waves
  }
  // epilogue
#pragma unroll
  for (int m = 0; m < 8; ++m)
#pragma unroll
    for (int n = 0; n < 4; ++n) {
      int row = brow + wr * 128 + m * 16 + lk * 4;
      int col = bcol + wc * 64 + n * 16 + lr;
#pragma unroll
      for (int j = 0; j < 4; ++j) {
        float v = acc[m][n][j];
        if constexpr (sizeof(OutT) == 2)
          C[(size_t)(row + j) * ldc + col] = (OutT)f2bf(v);
        else
          C[(size_t)(row + j) * ldc + col] = v;
      }
    }
}

// ---------- GEMM: C[M][ldc] = A[M][K] * BT[N][K]^T  (m97 structure) ----------
template <typename OutT>
__global__ __launch_bounds__(256) void gemm128_kernel(const ushort_t* __restrict__ A,
                                                      const ushort_t* __restrict__ BT,
                                                      OutT* __restrict__ C,
                                                      int M, int N, int K, int ldc) {
  __shared__ ushort_t As[128 * 32];
  __shared__ ushort_t Bs[128 * 32];
  int brow = blockIdx.y * 128, bcol = blockIdx.x * 128;
  int tid = threadIdx.x, w = tid >> 6, lane = tid & 63;
  int wr = w >> 1, wc = w & 1;
  int lr = lane & 15, lk = lane >> 4;
  f32x4 acc[4][4] = {};

  int srow = lane >> 2;
  int scol = (lane & 3) * 8;
  const ushort_t* Ab = A + (size_t)brow * K + scol;
  const ushort_t* Bb = BT + (size_t)bcol * K + scol;

  for (int kt = 0; kt < K; kt += 32) {
#pragma unroll
    for (int i = 0; i < 2; i++) {
      int seg = w * 2 + i;
      int row = seg * 16 + srow;
      load_lds16(Ab + (size_t)row * K + kt, (char*)As + seg * 1024);
      load_lds16(Bb + (size_t)row * K + kt, (char*)Bs + seg * 1024);
    }
    __syncthreads();
    bf16x8 af[4], bfr[4];
#pragma unroll
    for (int m = 0; m < 4; m++)
      af[m] = *(const bf16x8*)&As[(wr * 64 + m * 16 + lr) * 32 + lk * 8];
#pragma unroll
    for (int n = 0; n < 4; n++)
      bfr[n] = *(const bf16x8*)&Bs[(wc * 64 + n * 16 + lr) * 32 + lk * 8];
#pragma unroll
    for (int m = 0; m < 4; m++)
#pragma unroll
      for (int n = 0; n < 4; n++)
        acc[m][n] = __builtin_amdgcn_mfma_f32_16x16x32_bf16(af[m], bfr[n], acc[m][n], 0, 0, 0);
    __syncthreads();
  }
#pragma unroll
  for (int m = 0; m < 4; m++)
#pragma unroll
    for (int n = 0; n < 4; n++) {
      int row = brow + wr * 64 + m * 16 + lk * 4;
      int col = bcol + wc * 64 + n * 16 + lr;
#pragma unroll
      for (int j = 0; j < 4; j++) {
        float v = acc[m][n][j];
        if constexpr (sizeof(OutT) == 2)
          C[(size_t)(row + j) * ldc + col] = (OutT)f2bf(v);
        else
          C[(size_t)(row + j) * ldc + col] = v;
      }
    }
}

// ---------- gemmS: P[tile] = exp2(Q K^T) causal, materialized bf16 ----------
__global__ __launch_bounds__(256) void gemmS_kernel(const ushort_t* __restrict__ C1,
                                                    ushort_t* __restrict__ P) {
  int rem = blockIdx.x, rt = 0;
  while (rem > rt) { rem -= (rt + 1); rt++; }
  const int ct = rem;
  const int h = blockIdx.y, hk = h >> 2;

  __shared__ ushort_t As[128 * 32];
  __shared__ ushort_t Bs[128 * 32];
  int tid = threadIdx.x, w = tid >> 6, lane = tid & 63;
  int wr = w >> 1, wc = w & 1;
  int lr = lane & 15, lk = lane >> 4;
  f32x4 acc[4][4] = {};
  int srow = lane >> 2;
  int scol = (lane & 3) * 8;
  const ushort_t* Ab = C1 + (size_t)(rt * 128) * 6144 + h * 128 + scol;         // Q
  const ushort_t* Bb = C1 + (size_t)(ct * 128) * 6144 + 4096 + hk * 128 + scol; // K

  for (int kt = 0; kt < 128; kt += 32) {
#pragma unroll
    for (int i = 0; i < 2; i++) {
      int seg = w * 2 + i;
      int row = seg * 16 + srow;
      load_lds16(Ab + (size_t)row * 6144 + kt, (char*)As + seg * 1024);
      load_lds16(Bb + (size_t)row * 6144 + kt, (char*)Bs + seg * 1024);
    }
    __syncthreads();
    bf16x8 af[4], bfr[4];
#pragma unroll
    for (int m = 0; m < 4; m++)
      af[m] = *(const bf16x8*)&As[(wr * 64 + m * 16 + lr) * 32 + lk * 8];
#pragma unroll
    for (int n = 0; n < 4; n++)
      bfr[n] = *(const bf16x8*)&Bs[(wc * 64 + n * 16 + lr) * 32 + lk * 8];
#pragma unroll
    for (int m = 0; m < 4; m++)
#pragma unroll
      for (int n = 0; n < 4; n++)
        acc[m][n] = __builtin_amdgcn_mfma_f32_16x16x32_bf16(af[m], bfr[n], acc[m][n], 0, 0, 0);
    __syncthreads();
  }
  ushort_t* Pt = P + ((size_t)h * 136 + (size_t)(rt * (rt + 1) / 2) + ct) * 16384;
  const bool diag = (rt == ct);
#pragma unroll
  for (int m = 0; m < 4; m++)
#pragma unroll
    for (int n = 0; n < 4; n++) {
      int row = wr * 64 + m * 16 + lk * 4;
      int col = wc * 64 + n * 16 + lr;
#pragma unroll
      for (int j = 0; j < 4; j++) {
        float v = exp2_hw(acc[m][n][j]);
        if (diag && col > row + j) v = 0.f;
        Pt[(row + j) * 128 + col] = f2bf(v);
      }
    }
}

// ---------- rowsum: inv[h][r] = 1 / sum_k P[h][r][k] ----------
__global__ __launch_bounds__(256) void rowsum_kernel(const ushort_t* __restrict__ P,
                                                     float* __restrict__ inv) {
  int row = blockIdx.x * 4 + (threadIdx.x >> 6);  // 0..65535
  int lane = threadIdx.x & 63;
  int h = row >> 11, r = row & 2047;
  int rt = r >> 7, rr = r & 127;
  const ushort_t* Ph = P + ((size_t)h * 136 + (size_t)(rt * (rt + 1) / 2)) * 16384 + rr * 128;
  float s = 0.f;
  for (int ct0 = 0; ct0 <= rt; ct0 += 4) {
    int ct = ct0 + (lane >> 4);
    if (ct <= rt) {
      bf16x8 v = *(const bf16x8*)(Ph + (size_t)ct * 16384 + (lane & 15) * 8);
#pragma unroll
      for (int j = 0; j < 8; j++) s += bf2f((ushort_t)v[j]);
    }
  }
#pragma unroll
  for (int off = 1; off < 64; off <<= 1) s += __shfl_xor(s, off, 64);
  if (lane == 0) inv[row] = 1.0f / s;
}

// ---------- gemmPV: AO[rt-tile] = (P * V) * inv ----------
__global__ __launch_bounds__(256) void gemmPV_kernel(const ushort_t* __restrict__ P,
                                                     const ushort_t* __restrict__ VT,
                                                     const float* __restrict__ inv,
                                                     ushort_t* __restrict__ AO) {
  const int h = blockIdx.x, hk = h >> 2;
  const int rt = 15 - (int)blockIdx.y;

  __shared__ ushort_t As[128 * 32];
  __shared__ ushort_t Bs[128 * 32];
  int tid = threadIdx.x, w = tid >> 6, lane = tid & 63;
  int wr = w >> 1, wc = w & 1;
  int lr = lane & 15, lk = lane >> 4;
  f32x4 acc[4][4] = {};
  int srow = lane >> 2;
  int scol = (lane & 3) * 8;
  const ushort_t* Ph = P + ((size_t)h * 136 + (size_t)(rt * (rt + 1) / 2)) * 16384;
  const ushort_t* Vh = VT + (size_t)hk * 128 * 2048;

  const int nks = (rt + 1) * 4;
  for (int ks = 0; ks < nks; ks++) {
    int k0 = ks * 32;
    int ctk = k0 >> 7, kin = k0 & 127;
#pragma unroll
    for (int i = 0; i < 2; i++) {
      int seg = w * 2 + i;
      int row = seg * 16 + srow;
      load_lds16(Ph + (size_t)ctk * 16384 + (size_t)row * 128 + kin + scol,
                 (char*)As + seg * 1024);
      load_lds16(Vh + (size_t)row * 2048 + k0 + scol, (char*)Bs + seg * 1024);
    }
    __syncthreads();
    bf16x8 af[4], bfr[4];
#pragma unroll
    for (int m = 0; m < 4; m++)
      af[m] = *(const bf16x8*)&As[(wr * 64 + m * 16 + lr) * 32 + lk * 8];
#pragma unroll
    for (int n = 0; n < 4; n++)
      bfr[n] = *(const bf16x8*)&Bs[(wc * 64 + n * 16 + lr) * 32 + lk * 8];
#pragma unroll
    for (int m = 0; m < 4; m++)
#pragma unroll
      for (int n = 0; n < 4; n++)
        acc[m][n] = __builtin_amdgcn_mfma_f32_16x16x32_bf16(af[m], bfr[n], acc[m][n], 0, 0, 0);
    __syncthreads();
  }
  const int q0 = rt * 128;
#pragma unroll
  for (int m = 0; m < 4; m++)
#pragma unroll
    for (int n = 0; n < 4; n++) {
      int row = wr * 64 + m * 16 + lk * 4;
      int col = wc * 64 + n * 16 + lr;
#pragma unroll
      for (int j = 0; j < 4; j++) {
        float v = acc[m][n][j] * inv[h * 2048 + q0 + row + j];
        AO[(size_t)(q0 + row + j) * 4096 + h * 128 + col] = f2bf(v);
      }
    }
}

// ---------- flash attention (fallback when workspace too small) ----------
__global__ __launch_bounds__(256) void fattn_kernel(const ushort_t* __restrict__ C1,
                                                    const ushort_t* __restrict__ VT,
                                                    ushort_t* __restrict__ AO) {
  __shared__ ushort_t Pl[4][32][72];
  const int h = blockIdx.x, hk = h >> 2;
  const int qt = gridDim.y - 1 - blockIdx.y;
  const int tid = threadIdx.x, w = tid >> 6, lane = tid & 63;
  const int lq = lane & 31, hi = lane >> 5;
  const int qw0 = qt * 128 + w * 32;
  const int qabs = qw0 + lq;

  const ushort_t* Kb = C1 + 4096 + (size_t)hk * 128;
  const ushort_t* Vb = VT + (size_t)hk * 128 * 2048;

  bf16x8 qf[8];
  {
    const ushort_t* qrow = C1 + (size_t)qabs * 6144 + h * 128;
#pragma unroll
    for (int s = 0; s < 8; s++) qf[s] = *(const bf16x8*)(qrow + s * 16 + hi * 8);
  }
  f32x16 ot[4] = {};
  float mrow = -1e30f, ssum = 0.f;

  const int ktmax = (qw0 + 31) >> 6;
  for (int kt = 0; kt <= ktmax; kt++) {
    f32x16 sg[2] = {};
#pragma unroll
    for (int g = 0; g < 2; g++) {
      bf16x8 kfa[8];
      const ushort_t* krow = Kb + (size_t)(kt * 64 + g * 32 + lq) * 6144 + hi * 8;
#pragma unroll
      for (int s = 0; s < 8; s++) kfa[s] = *(const bf16x8*)(krow + s * 16);
#pragma unroll
      for (int s = 0; s < 8; s++)
        sg[g] = __builtin_amdgcn_mfma_f32_32x32x16_bf16(kfa[s], qf[s], sg[g], 0, 0, 0);
    }
    if (kt * 64 + 63 > qw0) {
#pragma unroll
      for (int g = 0; g < 2; g++)
#pragma unroll
        for (int r = 0; r < 16; r++) {
          int key = kt * 64 + g * 32 + (r & 3) + 8 * (r >> 2) + 4 * hi;
          if (key > qabs) sg[g][r] = -1e30f;
        }
    }
    float pm = -1e30f;
#pragma unroll
    for (int g = 0; g < 2; g++)
#pragma unroll
      for (int r = 0; r < 16; r++) pm = fmaxf(pm, sg[g][r]);
    pm = fmaxf(pm, __shfl_xor(pm, 32));
    float mnew = fmaxf(mrow, pm);
    float corr = exp2_hw(mrow - mnew);
    mrow = mnew;
    float ps = 0.f;
#pragma unroll
    for (int g = 0; g < 2; g++)
#pragma unroll
      for (int r = 0; r < 16; r++) {
        float e = exp2_hw(sg[g][r] - mnew);
        sg[g][r] = e;
        ps += e;
      }
    ps += __shfl_xor(ps, 32);
    ssum = ssum * corr + ps;
    if (!__all(corr == 1.f)) {
#pragma unroll
      for (int d = 0; d < 4; d++)
#pragma unroll
        for (int r = 0; r < 16; r++) ot[d][r] *= corr;
    }
#pragma unroll
    for (int g = 0; g < 2; g++)
#pragma unroll
      for (int rq = 0; rq < 4; rq++) {
        bf16x4 pk;
#pragma unroll
        for (int j = 0; j < 4; j++) pk[j] = (short)f2bf(sg[g][rq * 4 + j]);
        *(bf16x4*)&Pl[w][lq][g * 32 + rq * 8 + hi * 4] = pk;
      }
    asm volatile("s_waitcnt lgkmcnt(0)" ::: "memory");
    bf16x8 pf[4];
#pragma unroll
    for (int s = 0; s < 4; s++) pf[s] = *(const bf16x8*)&Pl[w][lq][s * 16 + hi * 8];
#pragma unroll
    for (int d = 0; d < 4; d++) {
      bf16x8 vfa[4];
      const ushort_t* vrow = Vb + (size_t)(d * 32 + lq) * 2048 + kt * 64 + hi * 8;
#pragma unroll
      for (int s = 0; s < 4; s++) vfa[s] = *(const bf16x8*)(vrow + s * 16);
#pragma unroll
      for (int s = 0; s < 4; s++)
        ot[d] = __builtin_amdgcn_mfma_f32_32x32x16_bf16(vfa[s], pf[s], ot[d], 0, 0, 0);
    }
  }
  const float inv = 1.0f / ssum;
  ushort_t* orow = AO + (size_t)qabs * 4096 + h * 128;
#pragma unroll
  for (int d = 0; d < 4; d++)
#pragma unroll
    for (int rq = 0; rq < 4; rq++) {
      bf16x4 ok;
#pragma unroll
      for (int j = 0; j < 4; j++) ok[j] = (short)f2bf(ot[d][rq * 4 + j] * inv);
      *(bf16x4*)(orow + d * 32 + rq * 8 + hi * 4) = ok;
    }
}

// ---------- launch ----------
extern "C" void kernel_launch(void* const* d_in, const int* in_sizes, int n_in,
                              void* d_out, int out_size, void* d_ws, size_t ws_size,
                              hipStream_t stream) {
  (void)in_sizes; (void)n_in; (void)out_size;
  const float* x    = (const float*)d_in[0];
  const float* wq   = (const float*)d_in[1];
  const float* wk   = (const float*)d_in[2];
  const float* wv   = (const float*)d_in[3];
  const float* wo   = (const float*)d_in[4];
  const float* cosb = (const float*)d_in[5];
  const float* sinb = (const float*)d_in[6];

  char* ws = (char*)d_ws;
  const bool fast = ws_size >= (215ull << 20);

  if (fast) {
    // layout (MiB): C1[0,24) VT[24,28) woT[28,60) xb[60,76) wT[76,124)
    //               P[60,196) (xb+wT dead after gemm1)  AO[196,212) inv[212,213)
    ushort_t* C1  = (ushort_t*)(ws);
    ushort_t* VT  = (ushort_t*)(ws + ((size_t)24 << 20));
    ushort_t* woT = (ushort_t*)(ws + ((size_t)28 << 20));
    ushort_t* xb  = (ushort_t*)(ws + ((size_t)60 << 20));
    ushort_t* wT  = (ushort_t*)(ws + ((size_t)76 << 20));
    ushort_t* P   = (ushort_t*)(ws + ((size_t)60 << 20));
    ushort_t* AO  = (ushort_t*)(ws + ((size_t)196 << 20));
    float*    inv = (float*)(ws + ((size_t)212 << 20));

    cvt_x_kernel<<<4096, 256, 0, stream>>>(x, xb);
    tr_cvt_kernel<<<dim3(64, 64), 256, 0, stream>>>(wq, wT, 4096, 4096);
    tr_cvt_kernel<<<dim3(16, 64), 256, 0, stream>>>(wk, wT + (size_t)4096 * 4096, 4096, 1024);
    tr_cvt_kernel<<<dim3(16, 64), 256, 0, stream>>>(wv, wT + (size_t)5120 * 4096, 4096, 1024);
    tr_cvt_kernel<<<dim3(64, 64), 256, 0, stream>>>(wo, woT, 4096, 4096);

    // QKV projection: 256^2 pipelined GEMM, grid 8x24 = 192 (192%8==0)
    gemm256_kernel<ushort_t><<<192, 512, 0, stream>>>(xb, wT, C1, 2048, 6144, 4096, 6144);
    rope_kernel<<<5120, 256, 0, stream>>>(C1, cosb, sinb);
    trv_kernel<<<dim3(16, 32), 256, 0, stream>>>(C1, VT);

    gemmS_kernel<<<dim3(136, 32), 256, 0, stream>>>(C1, P);
    rowsum_kernel<<<16384, 256, 0, stream>>>(P, inv);
    gemmPV_kernel<<<dim3(32, 16), 256, 0, stream>>>(P, VT, inv, AO);

    // output projection: grid 8x16 = 128 (128%8==0)
    gemm256_kernel<float><<<128, 512, 0, stream>>>(AO, woT, (float*)d_out, 2048, 4096, 4096, 4096);
  } else {
    // proven 92MiB layout + R7 fattn
    ushort_t* xb  = (ushort_t*)(ws);
    ushort_t* wT  = (ushort_t*)(ws + ((size_t)16 << 20));
    ushort_t* C1  = (ushort_t*)(ws + ((size_t)64 << 20));
    ushort_t* VT  = (ushort_t*)(ws + ((size_t)88 << 20));
    ushort_t* AO  = xb;
    ushort_t* woT = wT;

    cvt_x_kernel<<<4096, 256, 0, stream>>>(x, xb);
    tr_cvt_kernel<<<dim3(64, 64), 256, 0, stream>>>(wq, wT, 4096, 4096);
    tr_cvt_kernel<<<dim3(16, 64), 256, 0, stream>>>(wk, wT + (size_t)4096 * 4096, 4096, 1024);
    tr_cvt_kernel<<<dim3(16, 64), 256, 0, stream>>>(wv, wT + (size_t)5120 * 4096, 4096, 1024);
    gemm128_kernel<ushort_t><<<dim3(48, 16), 256, 0, stream>>>(xb, wT, C1, 2048, 6144, 4096, 6144);
    rope_kernel<<<5120, 256, 0, stream>>>(C1, cosb, sinb);
    trv_kernel<<<dim3(16, 32), 256, 0, stream>>>(C1, VT);
    tr_cvt_kernel<<<dim3(64, 64), 256, 0, stream>>>(wo, woT, 4096, 4096);
    fattn_kernel<<<dim3(32, 16), 256, 0, stream>>>(C1, VT, AO);
    gemm128_kernel<float><<<dim3(32, 16), 256, 0, stream>>>(AO, woT, (float*)d_out, 2048, 4096, 4096, 4096);
  }
}

// Round 10
// 393.254 us; speedup vs baseline: 1.1313x; 1.1313x over previous
//
#include <hip/hip_runtime.h>
#include <stdint.h>

typedef unsigned short ushort_t;
typedef short bf16x4 __attribute__((ext_vector_type(4)));
typedef short bf16x8 __attribute__((ext_vector_type(8)));
typedef float f32x4 __attribute__((ext_vector_type(4)));
typedef float f32x16 __attribute__((ext_vector_type(16)));
typedef float f32x4v __attribute__((ext_vector_type(4)));

// ---------- helpers ----------
__device__ __forceinline__ ushort_t f2bf(float f) {
  unsigned int u = __builtin_bit_cast(unsigned int, f);
  u += 0x7fffu + ((u >> 16) & 1u);
  return (ushort_t)(u >> 16);
}
__device__ __forceinline__ float bf2f(ushort_t h) {
  unsigned int u = ((unsigned int)h) << 16;
  return __builtin_bit_cast(float, u);
}
__device__ __forceinline__ float exp2_hw(float x) {
  return __builtin_amdgcn_exp2f(x);  // v_exp_f32: D = 2^S0
}
__device__ __forceinline__ void load_lds16(const void* g, void* l) {
  __builtin_amdgcn_global_load_lds(
      (const __attribute__((address_space(1))) void*)g,
      (__attribute__((address_space(3))) void*)l, 16, 0, 0);
}

// ---------- x fp32 -> bf16 ----------
__global__ __launch_bounds__(256) void cvt_x_kernel(const float* __restrict__ x,
                                                    ushort_t* __restrict__ xb) {
  int i = blockIdx.x * 256 + threadIdx.x;  // each thread: 8 elems
  const f32x4v* xv = (const f32x4v*)x;
  f32x4v a = xv[2 * i], b = xv[2 * i + 1];
  bf16x8 o;
  o[0] = (short)f2bf(a[0]); o[1] = (short)f2bf(a[1]);
  o[2] = (short)f2bf(a[2]); o[3] = (short)f2bf(a[3]);
  o[4] = (short)f2bf(b[0]); o[5] = (short)f2bf(b[1]);
  o[6] = (short)f2bf(b[2]); o[7] = (short)f2bf(b[3]);
  ((bf16x8*)xb)[i] = o;
}

// ---------- weight fp32 [R][C] -> bf16 transposed [C][R] ----------
__global__ __launch_bounds__(256) void tr_cvt_kernel(const float* __restrict__ src,
                                                     ushort_t* __restrict__ dst,
                                                     int R, int C) {
  __shared__ float tile[64][65];
  int r0 = blockIdx.y * 64, c0 = blockIdx.x * 64;
  int t = threadIdx.x;
#pragma unroll
  for (int i = 0; i < 16; i++) {
    int idx = t + i * 256;
    int r = idx >> 6, c = idx & 63;
    tile[r][c] = src[(size_t)(r0 + r) * C + c0 + c];
  }
  __syncthreads();
#pragma unroll
  for (int i = 0; i < 16; i++) {
    int idx = t + i * 256;
    int cr = idx >> 6, cc = idx & 63;
    dst[(size_t)(c0 + cr) * R + r0 + cc] = f2bf(tile[cc][cr]);
  }
}

// ---------- RoPE in-place on C1 (Q cols 0..4095 pre-scaled by scale*log2e) ----------
__global__ __launch_bounds__(256) void rope_kernel(ushort_t* __restrict__ C1,
                                                   const float* __restrict__ cosb,
                                                   const float* __restrict__ sinb) {
  int idx = blockIdx.x * 256 + threadIdx.x;  // 2048 * 640
  int s = idx / 640;
  int col0 = (idx % 640) * 8;
  int i0 = (col0 & 127) >> 1;
  const float qs = (col0 < 4096) ? 0.12753055296570565f : 1.0f;  // scale*log2e
  ushort_t* p = C1 + (size_t)s * 6144 + col0;
  bf16x8 v = *(const bf16x8*)p;
  bf16x8 o;
  const float* cr = cosb + s * 64 + i0;
  const float* sr = sinb + s * 64 + i0;
#pragma unroll
  for (int j = 0; j < 4; j++) {
    float tr = bf2f((ushort_t)v[2 * j]);
    float ti = bf2f((ushort_t)v[2 * j + 1]);
    float c = cr[j], sn = sr[j];
    o[2 * j] = (short)f2bf((tr * c - ti * sn) * qs);
    o[2 * j + 1] = (short)f2bf((tr * sn + ti * c) * qs);
  }
  *(bf16x8*)p = o;
}

// ---------- V part of C1 -> VT [1024][2048] (row = hk*128+d, col = s) ----------
__global__ __launch_bounds__(256) void trv_kernel(const ushort_t* __restrict__ C1,
                                                  ushort_t* __restrict__ VT) {
  __shared__ ushort_t tile[64][65];
  int c0 = blockIdx.x * 64;  // within 1024
  int r0 = blockIdx.y * 64;  // within 2048
  int t = threadIdx.x;
#pragma unroll
  for (int i = 0; i < 16; i++) {
    int idx = t + i * 256;
    int r = idx >> 6, c = idx & 63;
    tile[r][c] = C1[(size_t)(r0 + r) * 6144 + 5120 + c0 + c];
  }
  __syncthreads();
#pragma unroll
  for (int i = 0; i < 16; i++) {
    int idx = t + i * 256;
    int cr = idx >> 6, cc = idx & 63;
    VT[(size_t)(c0 + cr) * 2048 + r0 + cc] = tile[cc][cr];
  }
}

// ---------- GEMM 128x256, triple-buffered fine-phase pipeline ----------
// C[M][ldc] = A[M][K] * BT[N][K]^T. M%128==0, N%256==0, K%64==0, K/64>=3.
// grid 1D = (M/128)*(N/256), grid%8==0. 512 thr = 8 waves (2 Mrows x 4 Ncols),
// per-wave 64x64 output. LDS 144KB = 3 buffers (A 16KB + B 32KB each):
// stage(t+2) -> buf[(t+2)%3], untouched by tiles t,t+1 -> staging issues spread
// INSIDE compute phases (no clobber). Boundary: per-wave vmcnt(6) THEN raw
// s_barrier (own slice complete + all waves arrived => whole tile visible).
// Never vmcnt(0) mid-loop (T4). Swizzle: LDS chunk L holds global chunk
// (L&7)^(row&7); ds_read applies the same XOR (R9: 0 bank conflicts).
template <typename OutT>
__global__ __launch_bounds__(512, 1) void gemm128x256_kernel(const ushort_t* __restrict__ A,
                                                             const ushort_t* __restrict__ BT,
                                                             OutT* __restrict__ C,
                                                             int M, int N, int K, int ldc) {
  __shared__ ushort_t As[3][128 * 64];  // 48KB
  __shared__ ushort_t Bs[3][256 * 64];  // 96KB
  const int nbx = N >> 8;
  const int nwg = gridDim.x;
  const int id = blockIdx.x;
  const int wg = (id & 7) * (nwg >> 3) + (id >> 3);  // XCD-contiguous (nwg%8==0)
  const int brow = (wg / nbx) << 7, bcol = (wg % nbx) << 8;
  const int tid = threadIdx.x, w = tid >> 6, lane = tid & 63;
  const int wr = w >> 2, wc = w & 3;
  const int lr = lane & 15, lk = lane >> 4;

  const ushort_t* Ab = A + (size_t)brow * K;
  const ushort_t* Bb = BT + (size_t)bcol * K;

  auto stageA = [&](int t, int buf, int i) {  // i in 0..1 (128 rows x 64 cols)
    int L = i * 512 + tid;
    int r = L >> 3, sc = L & 7;
    load_lds16(Ab + (size_t)r * K + (t << 6) + ((sc ^ (r & 7)) << 3),
               (char*)&As[buf][0] + L * 16);
  };
  auto stageB = [&](int t, int buf, int i) {  // i in 0..3 (256 rows x 64 cols)
    int L = i * 512 + tid;
    int r = L >> 3, sc = L & 7;
    load_lds16(Bb + (size_t)r * K + (t << 6) + ((sc ^ (r & 7)) << 3),
               (char*)&Bs[buf][0] + L * 16);
  };

  f32x4 acc[4][4] = {};
  const int NT = K >> 6;

  // prologue: tiles 0,1 in flight (12 loads/thread); wait tile0 (6 remain)
#pragma unroll
  for (int i = 0; i < 2; ++i) stageA(0, 0, i);
#pragma unroll
  for (int i = 0; i < 4; ++i) stageB(0, 0, i);
#pragma unroll
  for (int i = 0; i < 2; ++i) stageA(1, 1, i);
#pragma unroll
  for (int i = 0; i < 4; ++i) stageB(1, 1, i);
  asm volatile("s_waitcnt vmcnt(6)" ::: "memory");
  asm volatile("s_barrier" ::: "memory");

  int cur = 0;
  for (int t = 0; t < NT; ++t) {
    const char* Ac = (const char*)&As[cur][0];
    const char* Bc = (const char*)&Bs[cur][0];
    const int nxt = (cur + 2 >= 3) ? cur - 1 : cur + 2;  // (cur+2)%3
    const bool pf = (t + 2 < NT);

    // ---- phase 0: A-frags(8) + B-frags n=0,1 (4) ; stage 3 ; MFMA n=0,1 ----
    bf16x8 af[4][2], bf01[2][2];
#pragma unroll
    for (int m = 0; m < 4; ++m)
#pragma unroll
      for (int ks = 0; ks < 2; ++ks) {
        int rA = wr * 64 + m * 16 + lr;
        af[m][ks] = *(const bf16x8*)(Ac + rA * 128 + (((ks * 4 + lk) ^ (rA & 7)) << 4));
      }
#pragma unroll
    for (int n = 0; n < 2; ++n)
#pragma unroll
      for (int ks = 0; ks < 2; ++ks) {
        int rB = wc * 64 + n * 16 + lr;
        bf01[n][ks] = *(const bf16x8*)(Bc + rB * 128 + (((ks * 4 + lk) ^ (rB & 7)) << 4));
      }
    if (pf) { stageA(t + 2, nxt, 0); stageA(t + 2, nxt, 1); stageB(t + 2, nxt, 0); }
    asm volatile("s_waitcnt lgkmcnt(0)" ::: "memory");
    __builtin_amdgcn_sched_barrier(0);
    __builtin_amdgcn_s_setprio(1);
#pragma unroll
    for (int m = 0; m < 4; ++m)
#pragma unroll
      for (int n = 0; n < 2; ++n)
#pragma unroll
        for (int ks = 0; ks < 2; ++ks)
          acc[m][n] = __builtin_amdgcn_mfma_f32_16x16x32_bf16(af[m][ks], bf01[n][ks],
                                                              acc[m][n], 0, 0, 0);
    __builtin_amdgcn_s_setprio(0);

    // ---- phase 1: B-frags n=2,3 (4) ; stage 3 ; MFMA n=2,3 ----
    bf16x8 bf23[2][2];
#pragma unroll
    for (int n = 0; n < 2; ++n)
#pragma unroll
      for (int ks = 0; ks < 2; ++ks) {
        int rB = wc * 64 + (n + 2) * 16 + lr;
        bf23[n][ks] = *(const bf16x8*)(Bc + rB * 128 + (((ks * 4 + lk) ^ (rB & 7)) << 4));
      }
    if (pf) { stageB(t + 2, nxt, 1); stageB(t + 2, nxt, 2); stageB(t + 2, nxt, 3); }
    asm volatile("s_waitcnt lgkmcnt(0)" ::: "memory");
    __builtin_amdgcn_sched_barrier(0);
    __builtin_amdgcn_s_setprio(1);
#pragma unroll
    for (int m = 0; m < 4; ++m)
#pragma unroll
      for (int n = 0; n < 2; ++n)
#pragma unroll
        for (int ks = 0; ks < 2; ++ks)
          acc[m][n + 2] = __builtin_amdgcn_mfma_f32_16x16x32_bf16(af[m][ks], bf23[n][ks],
                                                                  acc[m][n + 2], 0, 0, 0);
    __builtin_amdgcn_s_setprio(0);

    // ---- boundary: own t+1 slice landed, then all waves arrive ----
    if (pf)
      asm volatile("s_waitcnt vmcnt(6)" ::: "memory");
    else
      asm volatile("s_waitcnt vmcnt(0)" ::: "memory");
    asm volatile("s_barrier" ::: "memory");
    cur = (cur == 2) ? 0 : cur + 1;
  }
  // epilogue
#pragma unroll
  for (int m = 0; m < 4; ++m)
#pragma unroll
    for (int n = 0; n < 4; ++n) {
      int row = brow + wr * 64 + m * 16 + lk * 4;
      int col = bcol + wc * 64 + n * 16 + lr;
#pragma unroll
      for (int j = 0; j < 4; ++j) {
        float v = acc[m][n][j];
        if constexpr (sizeof(OutT) == 2)
          C[(size_t)(row + j) * ldc + col] = (OutT)f2bf(v);
        else
          C[(size_t)(row + j) * ldc + col] = v;
      }
    }
}

// ---------- GEMM: C[M][ldc] = A[M][K] * BT[N][K]^T  (m97 structure) ----------
template <typename OutT>
__global__ __launch_bounds__(256) void gemm128_kernel(const ushort_t* __restrict__ A,
                                                      const ushort_t* __restrict__ BT,
                                                      OutT* __restrict__ C,
                                                      int M, int N, int K, int ldc) {
  __shared__ ushort_t As[128 * 32];
  __shared__ ushort_t Bs[128 * 32];
  int brow = blockIdx.y * 128, bcol = blockIdx.x * 128;
  int tid = threadIdx.x, w = tid >> 6, lane = tid & 63;
  int wr = w >> 1, wc = w & 1;
  int lr = lane & 15, lk = lane >> 4;
  f32x4 acc[4][4] = {};

  int srow = lane >> 2;
  int scol = (lane & 3) * 8;
  const ushort_t* Ab = A + (size_t)brow * K + scol;
  const ushort_t* Bb = BT + (size_t)bcol * K + scol;

  for (int kt = 0; kt < K; kt += 32) {
#pragma unroll
    for (int i = 0; i < 2; i++) {
      int seg = w * 2 + i;
      int row = seg * 16 + srow;
      load_lds16(Ab + (size_t)row * K + kt, (char*)As + seg * 1024);
      load_lds16(Bb + (size_t)row * K + kt, (char*)Bs + seg * 1024);
    }
    __syncthreads();
    bf16x8 af[4], bfr[4];
#pragma unroll
    for (int m = 0; m < 4; m++)
      af[m] = *(const bf16x8*)&As[(wr * 64 + m * 16 + lr) * 32 + lk * 8];
#pragma unroll
    for (int n = 0; n < 4; n++)
      bfr[n] = *(const bf16x8*)&Bs[(wc * 64 + n * 16 + lr) * 32 + lk * 8];
#pragma unroll
    for (int m = 0; m < 4; m++)
#pragma unroll
      for (int n = 0; n < 4; n++)
        acc[m][n] = __builtin_amdgcn_mfma_f32_16x16x32_bf16(af[m], bfr[n], acc[m][n], 0, 0, 0);
    __syncthreads();
  }
#pragma unroll
  for (int m = 0; m < 4; m++)
#pragma unroll
    for (int n = 0; n < 4; n++) {
      int row = brow + wr * 64 + m * 16 + lk * 4;
      int col = bcol + wc * 64 + n * 16 + lr;
#pragma unroll
      for (int j = 0; j < 4; j++) {
        float v = acc[m][n][j];
        if constexpr (sizeof(OutT) == 2)
          C[(size_t)(row + j) * ldc + col] = (OutT)f2bf(v);
        else
          C[(size_t)(row + j) * ldc + col] = v;
      }
    }
}

// ---------- gemmS: P[tile] = exp2(Q K^T) causal, materialized bf16 ----------
__global__ __launch_bounds__(256) void gemmS_kernel(const ushort_t* __restrict__ C1,
                                                    ushort_t* __restrict__ P) {
  int rem = blockIdx.x, rt = 0;
  while (rem > rt) { rem -= (rt + 1); rt++; }
  const int ct = rem;
  const int h = blockIdx.y, hk = h >> 2;

  __shared__ ushort_t As[128 * 32];
  __shared__ ushort_t Bs[128 * 32];
  int tid = threadIdx.x, w = tid >> 6, lane = tid & 63;
  int wr = w >> 1, wc = w & 1;
  int lr = lane & 15, lk = lane >> 4;
  f32x4 acc[4][4] = {};
  int srow = lane >> 2;
  int scol = (lane & 3) * 8;
  const ushort_t* Ab = C1 + (size_t)(rt * 128) * 6144 + h * 128 + scol;         // Q
  const ushort_t* Bb = C1 + (size_t)(ct * 128) * 6144 + 4096 + hk * 128 + scol; // K

  for (int kt = 0; kt < 128; kt += 32) {
#pragma unroll
    for (int i = 0; i < 2; i++) {
      int seg = w * 2 + i;
      int row = seg * 16 + srow;
      load_lds16(Ab + (size_t)row * 6144 + kt, (char*)As + seg * 1024);
      load_lds16(Bb + (size_t)row * 6144 + kt, (char*)Bs + seg * 1024);
    }
    __syncthreads();
    bf16x8 af[4], bfr[4];
#pragma unroll
    for (int m = 0; m < 4; m++)
      af[m] = *(const bf16x8*)&As[(wr * 64 + m * 16 + lr) * 32 + lk * 8];
#pragma unroll
    for (int n = 0; n < 4; n++)
      bfr[n] = *(const bf16x8*)&Bs[(wc * 64 + n * 16 + lr) * 32 + lk * 8];
#pragma unroll
    for (int m = 0; m < 4; m++)
#pragma unroll
      for (int n = 0; n < 4; n++)
        acc[m][n] = __builtin_amdgcn_mfma_f32_16x16x32_bf16(af[m], bfr[n], acc[m][n], 0, 0, 0);
    __syncthreads();
  }
  ushort_t* Pt = P + ((size_t)h * 136 + (size_t)(rt * (rt + 1) / 2) + ct) * 16384;
  const bool diag = (rt == ct);
#pragma unroll
  for (int m = 0; m < 4; m++)
#pragma unroll
    for (int n = 0; n < 4; n++) {
      int row = wr * 64 + m * 16 + lk * 4;
      int col = wc * 64 + n * 16 + lr;
#pragma unroll
      for (int j = 0; j < 4; j++) {
        float v = exp2_hw(acc[m][n][j]);
        if (diag && col > row + j) v = 0.f;
        Pt[(row + j) * 128 + col] = f2bf(v);
      }
    }
}

// ---------- rowsum: inv[h][r] = 1 / sum_k P[h][r][k] ----------
__global__ __launch_bounds__(256) void rowsum_kernel(const ushort_t* __restrict__ P,
                                                     float* __restrict__ inv) {
  int row = blockIdx.x * 4 + (threadIdx.x >> 6);  // 0..65535
  int lane = threadIdx.x & 63;
  int h = row >> 11, r = row & 2047;
  int rt = r >> 7, rr = r & 127;
  const ushort_t* Ph = P + ((size_t)h * 136 + (size_t)(rt * (rt + 1) / 2)) * 16384 + rr * 128;
  float s = 0.f;
  for (int ct0 = 0; ct0 <= rt; ct0 += 4) {
    int ct = ct0 + (lane >> 4);
    if (ct <= rt) {
      bf16x8 v = *(const bf16x8*)(Ph + (size_t)ct * 16384 + (lane & 15) * 8);
#pragma unroll
      for (int j = 0; j < 8; j++) s += bf2f((ushort_t)v[j]);
    }
  }
#pragma unroll
  for (int off = 1; off < 64; off <<= 1) s += __shfl_xor(s, off, 64);
  if (lane == 0) inv[row] = 1.0f / s;
}

// ---------- gemmPV: AO[rt-tile] = (P * V) * inv ----------
__global__ __launch_bounds__(256) void gemmPV_kernel(const ushort_t* __restrict__ P,
                                                     const ushort_t* __restrict__ VT,
                                                     const float* __restrict__ inv,
                                                     ushort_t* __restrict__ AO) {
  const int h = blockIdx.x, hk = h >> 2;
  const int rt = 15 - (int)blockIdx.y;

  __shared__ ushort_t As[128 * 32];
  __shared__ ushort_t Bs[128 * 32];
  int tid = threadIdx.x, w = tid >> 6, lane = tid & 63;
  int wr = w >> 1, wc = w & 1;
  int lr = lane & 15, lk = lane >> 4;
  f32x4 acc[4][4] = {};
  int srow = lane >> 2;
  int scol = (lane & 3) * 8;
  const ushort_t* Ph = P + ((size_t)h * 136 + (size_t)(rt * (rt + 1) / 2)) * 16384;
  const ushort_t* Vh = VT + (size_t)hk * 128 * 2048;

  const int nks = (rt + 1) * 4;
  for (int ks = 0; ks < nks; ks++) {
    int k0 = ks * 32;
    int ctk = k0 >> 7, kin = k0 & 127;
#pragma unroll
    for (int i = 0; i < 2; i++) {
      int seg = w * 2 + i;
      int row = seg * 16 + srow;
      load_lds16(Ph + (size_t)ctk * 16384 + (size_t)row * 128 + kin + scol,
                 (char*)As + seg * 1024);
      load_lds16(Vh + (size_t)row * 2048 + k0 + scol, (char*)Bs + seg * 1024);
    }
    __syncthreads();
    bf16x8 af[4], bfr[4];
#pragma unroll
    for (int m = 0; m < 4; m++)
      af[m] = *(const bf16x8*)&As[(wr * 64 + m * 16 + lr) * 32 + lk * 8];
#pragma unroll
    for (int n = 0; n < 4; n++)
      bfr[n] = *(const bf16x8*)&Bs[(wc * 64 + n * 16 + lr) * 32 + lk * 8];
#pragma unroll
    for (int m = 0; m < 4; m++)
#pragma unroll
      for (int n = 0; n < 4; n++)
        acc[m][n] = __builtin_amdgcn_mfma_f32_16x16x32_bf16(af[m], bfr[n], acc[m][n], 0, 0, 0);
    __syncthreads();
  }
  const int q0 = rt * 128;
#pragma unroll
  for (int m = 0; m < 4; m++)
#pragma unroll
    for (int n = 0; n < 4; n++) {
      int row = wr * 64 + m * 16 + lk * 4;
      int col = wc * 64 + n * 16 + lr;
#pragma unroll
      for (int j = 0; j < 4; j++) {
        float v = acc[m][n][j] * inv[h * 2048 + q0 + row + j];
        AO[(size_t)(q0 + row + j) * 4096 + h * 128 + col] = f2bf(v);
      }
    }
}

// ---------- flash attention (fallback when workspace too small) ----------
__global__ __launch_bounds__(256) void fattn_kernel(const ushort_t* __restrict__ C1,
                                                    const ushort_t* __restrict__ VT,
                                                    ushort_t* __restrict__ AO) {
  __shared__ ushort_t Pl[4][32][72];
  const int h = blockIdx.x, hk = h >> 2;
  const int qt = gridDim.y - 1 - blockIdx.y;
  const int tid = threadIdx.x, w = tid >> 6, lane = tid & 63;
  const int lq = lane & 31, hi = lane >> 5;
  const int qw0 = qt * 128 + w * 32;
  const int qabs = qw0 + lq;

  const ushort_t* Kb = C1 + 4096 + (size_t)hk * 128;
  const ushort_t* Vb = VT + (size_t)hk * 128 * 2048;

  bf16x8 qf[8];
  {
    const ushort_t* qrow = C1 + (size_t)qabs * 6144 + h * 128;
#pragma unroll
    for (int s = 0; s < 8; s++) qf[s] = *(const bf16x8*)(qrow + s * 16 + hi * 8);
  }
  f32x16 ot[4] = {};
  float mrow = -1e30f, ssum = 0.f;

  const int ktmax = (qw0 + 31) >> 6;
  for (int kt = 0; kt <= ktmax; kt++) {
    f32x16 sg[2] = {};
#pragma unroll
    for (int g = 0; g < 2; g++) {
      bf16x8 kfa[8];
      const ushort_t* krow = Kb + (size_t)(kt * 64 + g * 32 + lq) * 6144 + hi * 8;
#pragma unroll
      for (int s = 0; s < 8; s++) kfa[s] = *(const bf16x8*)(krow + s * 16);
#pragma unroll
      for (int s = 0; s < 8; s++)
        sg[g] = __builtin_amdgcn_mfma_f32_32x32x16_bf16(kfa[s], qf[s], sg[g], 0, 0, 0);
    }
    if (kt * 64 + 63 > qw0) {
#pragma unroll
      for (int g = 0; g < 2; g++)
#pragma unroll
        for (int r = 0; r < 16; r++) {
          int key = kt * 64 + g * 32 + (r & 3) + 8 * (r >> 2) + 4 * hi;
          if (key > qabs) sg[g][r] = -1e30f;
        }
    }
    float pm = -1e30f;
#pragma unroll
    for (int g = 0; g < 2; g++)
#pragma unroll
      for (int r = 0; r < 16; r++) pm = fmaxf(pm, sg[g][r]);
    pm = fmaxf(pm, __shfl_xor(pm, 32));
    float mnew = fmaxf(mrow, pm);
    float corr = exp2_hw(mrow - mnew);
    mrow = mnew;
    float ps = 0.f;
#pragma unroll
    for (int g = 0; g < 2; g++)
#pragma unroll
      for (int r = 0; r < 16; r++) {
        float e = exp2_hw(sg[g][r] - mnew);
        sg[g][r] = e;
        ps += e;
      }
    ps += __shfl_xor(ps, 32);
    ssum = ssum * corr + ps;
    if (!__all(corr == 1.f)) {
#pragma unroll
      for (int d = 0; d < 4; d++)
#pragma unroll
        for (int r = 0; r < 16; r++) ot[d][r] *= corr;
    }
#pragma unroll
    for (int g = 0; g < 2; g++)
#pragma unroll
      for (int rq = 0; rq < 4; rq++) {
        bf16x4 pk;
#pragma unroll
        for (int j = 0; j < 4; j++) pk[j] = (short)f2bf(sg[g][rq * 4 + j]);
        *(bf16x4*)&Pl[w][lq][g * 32 + rq * 8 + hi * 4] = pk;
      }
    asm volatile("s_waitcnt lgkmcnt(0)" ::: "memory");
    bf16x8 pf[4];
#pragma unroll
    for (int s = 0; s < 4; s++) pf[s] = *(const bf16x8*)&Pl[w][lq][s * 16 + hi * 8];
#pragma unroll
    for (int d = 0; d < 4; d++) {
      bf16x8 vfa[4];
      const ushort_t* vrow = Vb + (size_t)(d * 32 + lq) * 2048 + kt * 64 + hi * 8;
#pragma unroll
      for (int s = 0; s < 4; s++) vfa[s] = *(const bf16x8*)(vrow + s * 16);
#pragma unroll
      for (int s = 0; s < 4; s++)
        ot[d] = __builtin_amdgcn_mfma_f32_32x32x16_bf16(vfa[s], pf[s], ot[d], 0, 0, 0);
    }
  }
  const float inv = 1.0f / ssum;
  ushort_t* orow = AO + (size_t)qabs * 4096 + h * 128;
#pragma unroll
  for (int d = 0; d < 4; d++)
#pragma unroll
    for (int rq = 0; rq < 4; rq++) {
      bf16x4 ok;
#pragma unroll
      for (int j = 0; j < 4; j++) ok[j] = (short)f2bf(ot[d][rq * 4 + j] * inv);
      *(bf16x4*)(orow + d * 32 + rq * 8 + hi * 4) = ok;
    }
}

// ---------- launch ----------
extern "C" void kernel_launch(void* const* d_in, const int* in_sizes, int n_in,
                              void* d_out, int out_size, void* d_ws, size_t ws_size,
                              hipStream_t stream) {
  (void)in_sizes; (void)n_in; (void)out_size;
  const float* x    = (const float*)d_in[0];
  const float* wq   = (const float*)d_in[1];
  const float* wk   = (const float*)d_in[2];
  const float* wv   = (const float*)d_in[3];
  const float* wo   = (const float*)d_in[4];
  const float* cosb = (const float*)d_in[5];
  const float* sinb = (const float*)d_in[6];

  char* ws = (char*)d_ws;
  const bool fast = ws_size >= (215ull << 20);

  if (fast) {
    // layout (MiB): C1[0,24) VT[24,28) woT[28,60) xb[60,76) wT[76,124)
    //               P[60,196) (xb+wT dead after gemm1)  AO[196,212) inv[212,213)
    ushort_t* C1  = (ushort_t*)(ws);
    ushort_t* VT  = (ushort_t*)(ws + ((size_t)24 << 20));
    ushort_t* woT = (ushort_t*)(ws + ((size_t)28 << 20));
    ushort_t* xb  = (ushort_t*)(ws + ((size_t)60 << 20));
    ushort_t* wT  = (ushort_t*)(ws + ((size_t)76 << 20));
    ushort_t* P   = (ushort_t*)(ws + ((size_t)60 << 20));
    ushort_t* AO  = (ushort_t*)(ws + ((size_t)196 << 20));
    float*    inv = (float*)(ws + ((size_t)212 << 20));

    cvt_x_kernel<<<4096, 256, 0, stream>>>(x, xb);
    tr_cvt_kernel<<<dim3(64, 64), 256, 0, stream>>>(wq, wT, 4096, 4096);
    tr_cvt_kernel<<<dim3(16, 64), 256, 0, stream>>>(wk, wT + (size_t)4096 * 4096, 4096, 1024);
    tr_cvt_kernel<<<dim3(16, 64), 256, 0, stream>>>(wv, wT + (size_t)5120 * 4096, 4096, 1024);
    tr_cvt_kernel<<<dim3(64, 64), 256, 0, stream>>>(wo, woT, 4096, 4096);

    // QKV projection: 128x256 pipelined GEMM, grid 16x24 = 384 (384%8==0)
    gemm128x256_kernel<ushort_t><<<384, 512, 0, stream>>>(xb, wT, C1, 2048, 6144, 4096, 6144);
    rope_kernel<<<5120, 256, 0, stream>>>(C1, cosb, sinb);
    trv_kernel<<<dim3(16, 32), 256, 0, stream>>>(C1, VT);

    gemmS_kernel<<<dim3(136, 32), 256, 0, stream>>>(C1, P);
    rowsum_kernel<<<16384, 256, 0, stream>>>(P, inv);
    gemmPV_kernel<<<dim3(32, 16), 256, 0, stream>>>(P, VT, inv, AO);

    // output projection: grid 16x16 = 256 (full chip, 256%8==0)
    gemm128x256_kernel<float><<<256, 512, 0, stream>>>(AO, woT, (float*)d_out, 2048, 4096, 4096, 4096);
  } else {
    // proven 92MiB layout + R7 fattn
    ushort_t* xb  = (ushort_t*)(ws);
    ushort_t* wT  = (ushort_t*)(ws + ((size_t)16 << 20));
    ushort_t* C1  = (ushort_t*)(ws + ((size_t)64 << 20));
    ushort_t* VT  = (ushort_t*)(ws + ((size_t)88 << 20));
    ushort_t* AO  = xb;
    ushort_t* woT = wT;

    cvt_x_kernel<<<4096, 256, 0, stream>>>(x, xb);
    tr_cvt_kernel<<<dim3(64, 64), 256, 0, stream>>>(wq, wT, 4096, 4096);
    tr_cvt_kernel<<<dim3(16, 64), 256, 0, stream>>>(wk, wT + (size_t)4096 * 4096, 4096, 1024);
    tr_cvt_kernel<<<dim3(16, 64), 256, 0, stream>>>(wv, wT + (size_t)5120 * 4096, 4096, 1024);
    gemm128_kernel<ushort_t><<<dim3(48, 16), 256, 0, stream>>>(xb, wT, C1, 2048, 6144, 4096, 6144);
    rope_kernel<<<5120, 256, 0, stream>>>(C1, cosb, sinb);
    trv_kernel<<<dim3(16, 32), 256, 0, stream>>>(C1, VT);
    tr_cvt_kernel<<<dim3(64, 64), 256, 0, stream>>>(wo, woT, 4096, 4096);
    fattn_kernel<<<dim3(32, 16), 256, 0, stream>>>(C1, VT, AO);
    gemm128_kernel<float><<<dim3(32, 16), 256, 0, stream>>>(AO, woT, (float*)d_out, 2048, 4096, 4096, 4096);
  }
}